// Round 1
// baseline (883.630 us; speedup 1.0000x reference)
//
#include <hip/hip_runtime.h>
#include <hip/hip_bf16.h>
#include <cstdint>

// Problem constants (static per reference: counts are all T/E = 2048)
#define E_   8
#define D_   768
#define H_   3072
#define T_   16384
#define SEG  2048

typedef __attribute__((ext_vector_type(8))) __bf16 bf16x8;
typedef __attribute__((ext_vector_type(4))) float f32x4;
typedef __attribute__((ext_vector_type(4))) unsigned int u32x4;

__device__ inline unsigned short f2bf(float f) {
  union { float f; unsigned int u; } v; v.f = f;
  unsigned int u = v.u;
  u += 0x7fffu + ((u >> 16) & 1u);   // round-to-nearest-even
  return (unsigned short)(u >> 16);
}

__device__ inline float gelu_exact(float x) {
  return 0.5f * x * (1.0f + erff(x * 0.70710678118654752f));
}

// ---- fp32 -> bf16 elementwise (x activation) ----
__global__ __launch_bounds__(256) void cvt_x_kernel(const float* __restrict__ in,
                                                    unsigned short* __restrict__ out,
                                                    int n8) {
  int i = blockIdx.x * 256 + threadIdx.x;
  if (i >= n8) return;
  const float* p = in + (size_t)i * 8;
  u32x4 v;
#pragma unroll
  for (int j = 0; j < 4; ++j)
    v[j] = (unsigned)f2bf(p[2 * j]) | ((unsigned)f2bf(p[2 * j + 1]) << 16);
  *(u32x4*)(out + (size_t)i * 8) = v;
}

// ---- weight transpose: [R][C][3] f32 -> [R][3][C] bf16 ----
__global__ __launch_bounds__(256) void cvt_w_kernel(const float* __restrict__ in,
                                                    unsigned short* __restrict__ out,
                                                    int C) {
  int r = blockIdx.x;
  const float* src = in + (size_t)r * C * 3;
  unsigned short* dst = out + (size_t)r * C * 3;
  for (int c = threadIdx.x; c < C; c += 256) {
    float v0 = src[c * 3 + 0], v1 = src[c * 3 + 1], v2 = src[c * 3 + 2];
    dst[0 * C + c] = f2bf(v0);
    dst[1 * C + c] = f2bf(v1);
    dst[2 * C + c] = f2bf(v2);
  }
}

// ---- grouped conv-GEMM, 128x128 tile, BK=64, 4 waves, 16x16x32 bf16 MFMA ----
// A: bf16 [T][CIN] activation (rows shifted by tap-1, zero-padded per segment)
// B (BPRE):  bf16 [E][COUT][3][CIN]  pre-transposed weights
// B (!BPRE): f32  [E][COUT][CIN][3]  original layout, strided reads (fallback)
template <int CIN, int COUT, bool DO_GELU, bool BPRE>
__global__ __launch_bounds__(256) void conv_gemm_kernel(
    const unsigned short* __restrict__ A,
    const unsigned short* __restrict__ Bt,
    const float* __restrict__ Braw,
    const float* __restrict__ bias,
    void* __restrict__ Out) {
  __shared__ __align__(16) unsigned short lds[16384];  // A tile 16KB @0, B tile 16KB @8192

  const int tid  = threadIdx.x;
  const int wave = tid >> 6, lane = tid & 63;
  const int e  = blockIdx.z;
  const int m0 = blockIdx.y * 128;
  const int n0 = blockIdx.x * 128;
  const int seg0 = e * SEG;
  const int wm = wave >> 1, wn = wave & 1;

  // staging lane mapping: piece pl of row r; swizzled dest piece = pl ^ (r&7)
  const int rsub = lane >> 3;           // row-within-8 (== r&7 for all calls)
  const int pl   = lane & 7;            // source 16B piece
  const int pd   = pl ^ rsub;           // swizzled LDS piece

  // fragment-read lane constants
  const int arow0 = (wm * 64 + (lane & 15)) * 128;          // byte offset, A tile
  const int brow0 = 16384 + (wn * 64 + (lane & 15)) * 128;  // byte offset, B tile
  const int kob   = (lane >> 4) * 16;
  const int axor  = (lane & 7) << 4;    // == (row&7)<<4 for every fragment row

  // accumulators pre-loaded with bias (per-column)
  f32x4 acc[4][4];
#pragma unroll
  for (int n = 0; n < 4; ++n) {
    const float bv = bias[e * COUT + n0 + wn * 64 + n * 16 + (lane & 15)];
#pragma unroll
    for (int m = 0; m < 4; ++m) acc[m][n] = (f32x4){bv, bv, bv, bv};
  }

  constexpr int CSTEPS = CIN / 64;
#pragma unroll 1
  for (int ks = 0; ks < 3 * CSTEPS; ++ks) {
    const int k3 = ks / CSTEPS;
    const int c0 = (ks - k3 * CSTEPS) * 64;

    // ---- stage A tile [128 rows][64 bf16], rows shifted by k3-1, zero-padded ----
#pragma unroll
    for (int i = 0; i < 4; ++i) {
      const int r  = (i * 4 + wave) * 8 + rsub;
      const int gm = m0 + r + k3 - 1;
      u32x4 v = {0u, 0u, 0u, 0u};
      if ((unsigned)gm < (unsigned)SEG)
        v = *(const u32x4*)(A + (size_t)(seg0 + gm) * CIN + c0 + pl * 8);
      *(u32x4*)(lds + r * 64 + pd * 8) = v;
    }

    // ---- stage B tile [128 rows][64 bf16] ----
    if (BPRE) {
#pragma unroll
      for (int i = 0; i < 4; ++i) {
        const int r = (i * 4 + wave) * 8 + rsub;
        u32x4 v = *(const u32x4*)(Bt + ((size_t)(e * COUT + n0 + r) * 3 + k3) * CIN + c0 + pl * 8);
        *(u32x4*)(lds + 8192 + r * 64 + pd * 8) = v;
      }
    } else {
      // fallback: gather fp32 weights at stride 3, convert, swizzled vector write
      const int r2  = tid >> 1;
      const int cb2 = (tid & 1) * 32;
      const float* wsrc = Braw + ((size_t)(e * COUT + n0 + r2) * CIN + c0 + cb2) * 3 + k3;
#pragma unroll
      for (int q = 0; q < 4; ++q) {
        u32x4 v;
#pragma unroll
        for (int jj = 0; jj < 4; ++jj)
          v[jj] = (unsigned)f2bf(wsrc[(q * 8 + 2 * jj) * 3]) |
                  ((unsigned)f2bf(wsrc[(q * 8 + 2 * jj + 1) * 3]) << 16);
        const int pdst = ((cb2 >> 3) + q) ^ (r2 & 7);
        *(u32x4*)(lds + 8192 + r2 * 64 + pdst * 8) = v;
      }
    }

    __syncthreads();

    // ---- compute: 2 k-slices x 4x4 fragments ----
#pragma unroll
    for (int s = 0; s < 2; ++s) {
      bf16x8 af[4], bfr[4];
#pragma unroll
      for (int m = 0; m < 4; ++m)
        af[m] = *(const bf16x8*)((const char*)lds + arow0 + m * 2048 + ((s * 64 + kob) ^ axor));
#pragma unroll
      for (int n = 0; n < 4; ++n)
        bfr[n] = *(const bf16x8*)((const char*)lds + brow0 + n * 2048 + ((s * 64 + kob) ^ axor));
#pragma unroll
      for (int m = 0; m < 4; ++m)
#pragma unroll
        for (int n = 0; n < 4; ++n)
          acc[m][n] = __builtin_amdgcn_mfma_f32_16x16x32_bf16(af[m], bfr[n], acc[m][n], 0, 0, 0);
    }

    __syncthreads();
  }

  // ---- epilogue: C/D layout col=lane&15, row=(lane>>4)*4+i ----
#pragma unroll
  for (int m = 0; m < 4; ++m) {
    const int rowb = m0 + wm * 64 + m * 16 + ((lane >> 4) << 2);
#pragma unroll
    for (int n = 0; n < 4; ++n) {
      const int col = n0 + wn * 64 + n * 16 + (lane & 15);
#pragma unroll
      for (int i = 0; i < 4; ++i) {
        const size_t off = (size_t)(seg0 + rowb + i) * COUT + col;
        if (DO_GELU)
          ((unsigned short*)Out)[off] = f2bf(gelu_exact(acc[m][n][i]));
        else
          ((float*)Out)[off] = acc[m][n][i];
      }
    }
  }
}

extern "C" void kernel_launch(void* const* d_in, const int* in_sizes, int n_in,
                              void* d_out, int out_size, void* d_ws, size_t ws_size,
                              hipStream_t stream) {
  const float* inp = (const float*)d_in[0];
  // d_in[1] = fwd_expert_count (all SEG=2048, static per problem)
  const float* w1 = (const float*)d_in[2];
  const float* b1 = (const float*)d_in[3];
  const float* w2 = (const float*)d_in[4];
  const float* b2 = (const float*)d_in[5];
  float* out = (float*)d_out;
  char* ws = (char*)d_ws;

  const size_t szXb = (size_t)T_ * D_ * 2;           // 25.2 MB
  const size_t szHb = (size_t)T_ * H_ * 2;           // 100.7 MB
  const size_t szW1 = (size_t)E_ * H_ * 3 * D_ * 2;  // 113.2 MB
  const size_t szW2 = (size_t)E_ * D_ * 3 * H_ * 2;  // 113.2 MB

  unsigned short* Xb  = (unsigned short*)ws;
  unsigned short* Hb  = (unsigned short*)(ws + szXb);
  unsigned short* W1T = (unsigned short*)(ws + szXb + szHb);
  unsigned short* W2T = (unsigned short*)(ws + szXb + szHb + szW1);

  const size_t NEED_MIN  = szXb + szHb;               // ~120 MiB
  const size_t NEED_FULL = szXb + szHb + szW1 + szW2; // ~336 MiB
  if (ws_size < NEED_MIN) return;  // cannot run; leaves zeros (diagnostic signature)
  const bool full = ws_size >= NEED_FULL;

  cvt_x_kernel<<<(T_ * D_ / 8 + 255) / 256, 256, 0, stream>>>(inp, Xb, T_ * D_ / 8);

  if (full) {
    cvt_w_kernel<<<E_ * H_, 256, 0, stream>>>(w1, W1T, D_);
    cvt_w_kernel<<<E_ * D_, 256, 0, stream>>>(w2, W2T, H_);
    conv_gemm_kernel<D_, H_, true, true>
        <<<dim3(H_ / 128, SEG / 128, E_), 256, 0, stream>>>(Xb, W1T, nullptr, b1, Hb);
    conv_gemm_kernel<H_, D_, false, true>
        <<<dim3(D_ / 128, SEG / 128, E_), 256, 0, stream>>>(Hb, W2T, nullptr, b2, out);
  } else {
    conv_gemm_kernel<D_, H_, true, false>
        <<<dim3(H_ / 128, SEG / 128, E_), 256, 0, stream>>>(Xb, nullptr, w1, b1, Hb);
    conv_gemm_kernel<H_, D_, false, false>
        <<<dim3(D_ / 128, SEG / 128, E_), 256, 0, stream>>>(Hb, nullptr, w2, b2, out);
  }
}